// Round 2
// baseline (2946.462 us; speedup 1.0000x reference)
//
#include <hip/hip_runtime.h>

// ---------------------------------------------------------------------------
// PointTransformerConv block, MI355X.  Low-workspace fused design (~128 MB):
//  1. k_node: h = LN(relu(x@W_in+b)); q,k,v = h@{W_dst,W_src,W_lin}  (fp32)
//  2. k_edge: per 64-edge tile, fp32 LDS GEMMs:
//       delta = mlp2(pos[dst]-pos[src]);  alpha = relu(mlp2(q[dst]-k[src]+delta))
//       since alpha>=0 and O(1), exp(alpha) is fp32-safe without max-subtract:
//       atomicAdd sg[dst,c] += exp(alpha);  accg[dst,c] += exp(alpha)*(v[src,c]+delta)
//     (ratio identical to reference's max-subtracted softmax)
//  3. k_out: out = relu((accg/(sg+1e-16)) @ W_out + b_out)
// No edge sort, no per-edge materialization.  ws = 5 * N*64*4B = 128 MB.
// ---------------------------------------------------------------------------

// 64x64x64 fp32 GEMM from LDS tiles. Thread layout: tn=t/16 rows, tc=t%16 cols,
// each thread accumulates a 4x4 tile. A stride sa (padded 68), B stride sb (64).
__device__ inline void gemm64(const float* A, int sa, const float* B, int sb,
                              float acc[4][4], int tn, int tc) {
#pragma unroll 2
  for (int k = 0; k < 64; k += 4) {
    float4 a[4], b[4];
#pragma unroll
    for (int i = 0; i < 4; ++i)
      a[i] = *(const float4*)(A + (tn * 4 + i) * sa + k);
#pragma unroll
    for (int kk = 0; kk < 4; ++kk)
      b[kk] = *(const float4*)(B + (k + kk) * sb + tc * 4);
#pragma unroll
    for (int i = 0; i < 4; ++i) {
      const float* av = (const float*)&a[i];
#pragma unroll
      for (int kk = 0; kk < 4; ++kk) {
        const float* bv = (const float*)&b[kk];
        acc[i][0] = fmaf(av[kk], bv[0], acc[i][0]);
        acc[i][1] = fmaf(av[kk], bv[1], acc[i][1]);
        acc[i][2] = fmaf(av[kk], bv[2], acc[i][2]);
        acc[i][3] = fmaf(av[kk], bv[3], acc[i][3]);
      }
    }
  }
}

// ------------------------------ node kernel --------------------------------

__global__ __launch_bounds__(256) void k_node(
    const float* __restrict__ x, const float* __restrict__ W_in,
    const float* __restrict__ b_in, const float* __restrict__ ln_g,
    const float* __restrict__ ln_b, const float* __restrict__ W_dst,
    const float* __restrict__ W_src, const float* __restrict__ W_lin,
    float* __restrict__ qg, float* __restrict__ kg, float* __restrict__ vg, int N) {
  __shared__ __align__(16) float Xt[64 * 68];
  __shared__ __align__(16) float Ht[64 * 68];
  __shared__ __align__(16) float Wt[64 * 64];
  int t = threadIdx.x;
  int n0 = blockIdx.x * 64;
  int tn = t >> 4, tc = t & 15;

#pragma unroll
  for (int r = 0; r < 16; ++r) {
    int idx = r * 256 + t;
    int nl = idx >> 6, c = idx & 63;
    int n = n0 + nl;
    Xt[nl * 68 + c] = (n < N) ? x[(size_t)n * 64 + c] : 0.f;
    Wt[idx] = W_in[idx];
  }
  __syncthreads();

  float acc[4][4] = {};
  gemm64(Xt, 68, Wt, 64, acc, tn, tc);
#pragma unroll
  for (int i = 0; i < 4; ++i)
#pragma unroll
    for (int j = 0; j < 4; ++j) {
      float v = acc[i][j] + b_in[tc * 4 + j];
      Ht[(tn * 4 + i) * 68 + tc * 4 + j] = fmaxf(v, 0.f);
    }
  __syncthreads();

  // LayerNorm: 4 threads per node row
  {
    int nl = t >> 2, qq = t & 3;
    float s = 0.f, ss = 0.f;
#pragma unroll
    for (int c = qq * 16; c < qq * 16 + 16; ++c) {
      float v = Ht[nl * 68 + c];
      s += v; ss += v * v;
    }
    s += __shfl_xor(s, 1);  s += __shfl_xor(s, 2);
    ss += __shfl_xor(ss, 1); ss += __shfl_xor(ss, 2);
    float mu = s * (1.f / 64.f);
    float var = ss * (1.f / 64.f) - mu * mu;
    float rs = rsqrtf(var + 1e-5f);
#pragma unroll
    for (int c = qq * 16; c < qq * 16 + 16; ++c) {
      float v = (Ht[nl * 68 + c] - mu) * rs * ln_g[c] + ln_b[c];
      Ht[nl * 68 + c] = v;
    }
  }
  __syncthreads();

  const float* Ws[3] = {W_dst, W_src, W_lin};
  float* Og[3] = {qg, kg, vg};
#pragma unroll 1
  for (int m = 0; m < 3; ++m) {
#pragma unroll
    for (int r = 0; r < 16; ++r) {
      int idx = r * 256 + t;
      Wt[idx] = Ws[m][idx];
    }
    __syncthreads();
    float a2[4][4] = {};
    gemm64(Ht, 68, Wt, 64, a2, tn, tc);
#pragma unroll
    for (int i = 0; i < 4; ++i) {
      int n = n0 + tn * 4 + i;
      if (n < N)
        *(float4*)&Og[m][(size_t)n * 64 + tc * 4] =
            make_float4(a2[i][0], a2[i][1], a2[i][2], a2[i][3]);
    }
    __syncthreads();
  }
}

// ------------------------------ edge kernel --------------------------------

__global__ __launch_bounds__(256) void k_edge(
    const int* __restrict__ src, const int* __restrict__ dst,
    const float* __restrict__ pos, const float* __restrict__ qg,
    const float* __restrict__ kg, const float* __restrict__ vg,
    const float* __restrict__ pn_W1, const float* __restrict__ pn_b1,
    const float* __restrict__ pn_W2, const float* __restrict__ pn_b2,
    const float* __restrict__ an_W1, const float* __restrict__ an_b1,
    const float* __restrict__ an_W2, const float* __restrict__ an_b2,
    float* __restrict__ sg, float* __restrict__ accg, int E) {
  __shared__ __align__(16) float A[64 * 68];   // ai, then a1
  __shared__ __align__(16) float D[64 * 68];   // delta, then payload
  __shared__ __align__(16) float Wt[64 * 64];
  __shared__ float PD[64 * 4];
  __shared__ int Ss[64], Sd[64];
  int t = threadIdx.x;
  int tn = t >> 4, tc = t & 15;
  long e0 = (long)blockIdx.x * 64;

  if (t < 64) {
    long e = e0 + t;
    int s_ = (e < E) ? src[e] : 0;
    int d_ = (e < E) ? dst[e] : 0;
    Ss[t] = s_; Sd[t] = d_;
    PD[t * 4 + 0] = pos[d_ * 3 + 0] - pos[s_ * 3 + 0];
    PD[t * 4 + 1] = pos[d_ * 3 + 1] - pos[s_ * 3 + 1];
    PD[t * 4 + 2] = pos[d_ * 3 + 2] - pos[s_ * 3 + 2];
  }
#pragma unroll
  for (int r = 0; r < 16; ++r) Wt[r * 256 + t] = pn_W2[r * 256 + t];
  __syncthreads();

  // layer1 of pos MLP (K=3): A = relu(pd @ pn_W1 + b1)
#pragma unroll
  for (int i = 0; i < 4; ++i) {
    int row = tn * 4 + i;
    float p0 = PD[row * 4 + 0], p1 = PD[row * 4 + 1], p2 = PD[row * 4 + 2];
#pragma unroll
    for (int j = 0; j < 4; ++j) {
      int c = tc * 4 + j;
      float v = fmaf(p0, pn_W1[c],
                fmaf(p1, pn_W1[64 + c],
                fmaf(p2, pn_W1[128 + c], pn_b1[c])));
      A[row * 68 + c] = fmaxf(v, 0.f);
    }
  }
  __syncthreads();

  // delta = relu(A @ pn_W2 + b2)  -> D
  {
    float acc[4][4] = {};
    gemm64(A, 68, Wt, 64, acc, tn, tc);
    __syncthreads();   // readers of A done before overwrite below
#pragma unroll
    for (int i = 0; i < 4; ++i)
#pragma unroll
      for (int j = 0; j < 4; ++j)
        D[(tn * 4 + i) * 68 + tc * 4 + j] =
            fmaxf(acc[i][j] + pn_b2[tc * 4 + j], 0.f);
  }
  __syncthreads();

  // A = q[dst]-k[src]+delta;  D (in place) = payload = v[src]+delta;  Wt = an_W1
#pragma unroll
  for (int r = 0; r < 16; ++r) {
    int idx = r * 256 + t;
    int el = idx >> 6, c = idx & 63;
    float dl = D[el * 68 + c];
    A[el * 68 + c] = qg[(size_t)Sd[el] * 64 + c] - kg[(size_t)Ss[el] * 64 + c] + dl;
    D[el * 68 + c] = vg[(size_t)Ss[el] * 64 + c] + dl;
    Wt[idx] = an_W1[idx];
  }
  __syncthreads();

  // a1 = relu(A @ an_W1 + an_b1) -> back into A;  Wt = an_W2
  {
    float acc[4][4] = {};
    gemm64(A, 68, Wt, 64, acc, tn, tc);
    __syncthreads();   // all reads of A / Wt complete
#pragma unroll
    for (int i = 0; i < 4; ++i)
#pragma unroll
      for (int j = 0; j < 4; ++j)
        A[(tn * 4 + i) * 68 + tc * 4 + j] =
            fmaxf(acc[i][j] + an_b1[tc * 4 + j], 0.f);
#pragma unroll
    for (int r = 0; r < 16; ++r) Wt[r * 256 + t] = an_W2[r * 256 + t];
  }
  __syncthreads();

  // alpha = relu(A @ an_W2 + an_b2); e=exp(alpha); atomic accumulate per dst
  {
    float acc[4][4] = {};
    gemm64(A, 68, Wt, 64, acc, tn, tc);
#pragma unroll
    for (int i = 0; i < 4; ++i) {
      long e = e0 + tn * 4 + i;
      if (e < E) {
        int d = Sd[tn * 4 + i];
#pragma unroll
        for (int j = 0; j < 4; ++j) {
          int c = tc * 4 + j;
          float al = fmaxf(acc[i][j] + an_b2[c], 0.f);
          float ex = __expf(al);
          atomicAdd(&sg[(size_t)d * 64 + c], ex);
          atomicAdd(&accg[(size_t)d * 64 + c], ex * D[(tn * 4 + i) * 68 + c]);
        }
      }
    }
  }
}

// ------------------------------ out kernel ---------------------------------

__global__ __launch_bounds__(256) void k_out(const float* __restrict__ accg,
                                             const float* __restrict__ sg,
                                             const float* __restrict__ W,
                                             const float* __restrict__ b,
                                             float* __restrict__ out, int N) {
  __shared__ __align__(16) float Xt[64 * 68];
  __shared__ __align__(16) float Wt[64 * 64];
  int t = threadIdx.x;
  int n0 = blockIdx.x * 64;
  int tn = t >> 4, tc = t & 15;
#pragma unroll
  for (int r = 0; r < 16; ++r) {
    int idx = r * 256 + t;
    int nl = idx >> 6, c = idx & 63;
    int n = n0 + nl;
    float v = 0.f;
    if (n < N) {
      size_t o = (size_t)n * 64 + c;
      v = accg[o] / (sg[o] + 1e-16f);
    }
    Xt[nl * 68 + c] = v;
    Wt[idx] = W[idx];
  }
  __syncthreads();
  float acc[4][4] = {};
  gemm64(Xt, 68, Wt, 64, acc, tn, tc);
#pragma unroll
  for (int i = 0; i < 4; ++i) {
    int n = n0 + tn * 4 + i;
    if (n < N) {
      float4 o;
      o.x = fmaxf(acc[i][0] + b[tc * 4 + 0], 0.f);
      o.y = fmaxf(acc[i][1] + b[tc * 4 + 1], 0.f);
      o.z = fmaxf(acc[i][2] + b[tc * 4 + 2], 0.f);
      o.w = fmaxf(acc[i][3] + b[tc * 4 + 3], 0.f);
      *(float4*)&out[(size_t)n * 64 + tc * 4] = o;
    }
  }
}

// ------------------------------- launcher ----------------------------------

extern "C" void kernel_launch(void* const* d_in, const int* in_sizes, int n_in,
                              void* d_out, int out_size, void* d_ws, size_t ws_size,
                              hipStream_t stream) {
  const float* x     = (const float*)d_in[0];
  const float* pos   = (const float*)d_in[1];
  const int*   eidx  = (const int*)d_in[2];
  const float* W_in  = (const float*)d_in[3];
  const float* b_in  = (const float*)d_in[4];
  const float* ln_g  = (const float*)d_in[5];
  const float* ln_b  = (const float*)d_in[6];
  const float* W_lin = (const float*)d_in[7];
  const float* W_src = (const float*)d_in[8];
  const float* W_dst = (const float*)d_in[9];
  const float* pn_W1 = (const float*)d_in[10];
  const float* pn_b1 = (const float*)d_in[11];
  const float* pn_W2 = (const float*)d_in[12];
  const float* pn_b2 = (const float*)d_in[13];
  const float* an_W1 = (const float*)d_in[14];
  const float* an_b1 = (const float*)d_in[15];
  const float* an_W2 = (const float*)d_in[16];
  const float* an_b2 = (const float*)d_in[17];
  const float* W_out = (const float*)d_in[18];
  const float* b_out = (const float*)d_in[19];
  float* out = (float*)d_out;

  int N = in_sizes[0] / 64;
  int E = in_sizes[2] / 2;
  const int* src = eidx;
  const int* dst = eidx + E;

  char* w = (char*)d_ws;
  auto alloc = [&](size_t bytes) -> void* {
    void* p = (void*)w;
    w += (bytes + 255) & ~(size_t)255;
    return p;
  };
  float* qg   = (float*)alloc((size_t)N * 64 * 4);
  float* kg   = (float*)alloc((size_t)N * 64 * 4);
  float* vg   = (float*)alloc((size_t)N * 64 * 4);
  float* sg   = (float*)alloc((size_t)N * 64 * 4);
  float* accg = (float*)alloc((size_t)N * 64 * 4);   // contiguous after sg

  // zero softmax accumulators (ws is poisoned 0xAA before every launch)
  hipMemsetAsync(sg, 0, (size_t)N * 64 * 4 * 2, stream);

  k_node<<<(N + 63) / 64, 256, 0, stream>>>(x, W_in, b_in, ln_g, ln_b,
                                            W_dst, W_src, W_lin, qg, kg, vg, N);
  k_edge<<<(E + 63) / 64, 256, 0, stream>>>(src, dst, pos, qg, kg, vg,
                                            pn_W1, pn_b1, pn_W2, pn_b2,
                                            an_W1, an_b1, an_W2, an_b2,
                                            sg, accg, E);
  k_out<<<(N + 63) / 64, 256, 0, stream>>>(accg, sg, W_out, b_out, out, N);
}

// Round 3
// 1015.477 us; speedup vs baseline: 2.9016x; 2.9016x over previous
//
#include <hip/hip_runtime.h>

// ---------------------------------------------------------------------------
// PointTransformerConv block, MI355X.  R3: dst-sorted edges + fused segmented
// reduction (atomics cut ~13x vs R2's per-edge-channel atomicAdd).
//  1. counting sort edges by dst (hist -> scan -> scatter)
//  2. k_node: h = LN(relu(x@W_in+b)); q,k,v = h@{W_dst,W_src,W_lin}  (fp32)
//  3. k_edge (64 sorted edges/block): fp32 LDS GEMMs
//       delta = mlp2(pos[dst]-pos[src]); alpha = relu(mlp2(q[dst]-k[src]+delta))
//       ex = exp(alpha)  [alpha>=0, O(1): no max-subtract needed, ratio exact]
//       segmented per-dst run reduction in-block, one atomicAdd per run/chan:
//         sg[dst,c] += sum ex ; accg[dst,c] += sum ex*(v[src,c]+delta)
//  4. k_out: out = relu((accg/(sg+1e-16)) @ W_out + b_out)
// ---------------------------------------------------------------------------

// 64x64x64 fp32 GEMM from LDS tiles. tn=t/16 rows, tc=t%16 cols, 4x4/thread.
__device__ inline void gemm64(const float* A, int sa, const float* B, int sb,
                              float acc[4][4], int tn, int tc) {
#pragma unroll 2
  for (int k = 0; k < 64; k += 4) {
    float4 a[4], b[4];
#pragma unroll
    for (int i = 0; i < 4; ++i)
      a[i] = *(const float4*)(A + (tn * 4 + i) * sa + k);
#pragma unroll
    for (int kk = 0; kk < 4; ++kk)
      b[kk] = *(const float4*)(B + (k + kk) * sb + tc * 4);
#pragma unroll
    for (int i = 0; i < 4; ++i) {
      const float* av = (const float*)&a[i];
#pragma unroll
      for (int kk = 0; kk < 4; ++kk) {
        const float* bv = (const float*)&b[kk];
        acc[i][0] = fmaf(av[kk], bv[0], acc[i][0]);
        acc[i][1] = fmaf(av[kk], bv[1], acc[i][1]);
        acc[i][2] = fmaf(av[kk], bv[2], acc[i][2]);
        acc[i][3] = fmaf(av[kk], bv[3], acc[i][3]);
      }
    }
  }
}

// ------------------------------ sort kernels -------------------------------

__global__ void k_hist(const int* __restrict__ dst, int* __restrict__ hist, int E) {
  int e = blockIdx.x * 256 + threadIdx.x;
  if (e < E) atomicAdd(&hist[dst[e]], 1);
}

__global__ __launch_bounds__(256) void k_scan1(const int* __restrict__ hist,
                                               int* __restrict__ incl,
                                               int* __restrict__ bsum, int N) {
  __shared__ int sd[256];
  int t = threadIdx.x;
  int base = blockIdx.x * 1024 + t * 4;
  int v[4]; int ts = 0;
#pragma unroll
  for (int i = 0; i < 4; ++i) {
    int idx = base + i;
    v[i] = (idx < N) ? hist[idx] : 0;
    ts += v[i];
  }
  sd[t] = ts;
  __syncthreads();
  for (int off = 1; off < 256; off <<= 1) {
    int xv = (t >= off) ? sd[t - off] : 0;
    __syncthreads();
    sd[t] += xv;
    __syncthreads();
  }
  int run = sd[t] - ts;   // exclusive prefix for this thread
#pragma unroll
  for (int i = 0; i < 4; ++i) {
    run += v[i];
    int idx = base + i;
    if (idx < N) incl[idx] = run;     // block-local inclusive
  }
  if (t == 255) bsum[blockIdx.x] = sd[255];
}

__global__ void k_scan2(const int* __restrict__ bsum, int* __restrict__ boff, int nb) {
  __shared__ int sd[128];
  int t = threadIdx.x;
  int v = (t < nb) ? bsum[t] : 0;
  sd[t] = v;
  __syncthreads();
  for (int off = 1; off < 128; off <<= 1) {
    int xv = (t >= off) ? sd[t - off] : 0;
    __syncthreads();
    sd[t] += xv;
    __syncthreads();
  }
  if (t < nb) boff[t] = sd[t] - v;    // exclusive
}

__global__ void k_scan3(const int* __restrict__ incl, const int* __restrict__ hist,
                        const int* __restrict__ boff, int* __restrict__ cursor,
                        int N) {
  int base = blockIdx.x * 1024 + threadIdx.x * 4;
  int bo = boff[blockIdx.x];
#pragma unroll
  for (int i = 0; i < 4; ++i) {
    int id = base + i;
    if (id < N) cursor[id] = bo + incl[id] - hist[id];  // global exclusive
  }
}

__global__ void k_scatter(const int* __restrict__ src, const int* __restrict__ dst,
                          int* __restrict__ cursor, int* __restrict__ ssrc,
                          int* __restrict__ sdst, int E) {
  int e = blockIdx.x * 256 + threadIdx.x;
  if (e < E) {
    int d = dst[e];
    int p = atomicAdd(&cursor[d], 1);
    ssrc[p] = src[e];
    sdst[p] = d;
  }
}

// ------------------------------ node kernel --------------------------------

__global__ __launch_bounds__(256) void k_node(
    const float* __restrict__ x, const float* __restrict__ W_in,
    const float* __restrict__ b_in, const float* __restrict__ ln_g,
    const float* __restrict__ ln_b, const float* __restrict__ W_dst,
    const float* __restrict__ W_src, const float* __restrict__ W_lin,
    float* __restrict__ qg, float* __restrict__ kg, float* __restrict__ vg, int N) {
  __shared__ __align__(16) float Xt[64 * 68];
  __shared__ __align__(16) float Ht[64 * 68];
  __shared__ __align__(16) float Wt[64 * 64];
  int t = threadIdx.x;
  int n0 = blockIdx.x * 64;
  int tn = t >> 4, tc = t & 15;

#pragma unroll
  for (int r = 0; r < 16; ++r) {
    int idx = r * 256 + t;
    int nl = idx >> 6, c = idx & 63;
    int n = n0 + nl;
    Xt[nl * 68 + c] = (n < N) ? x[(size_t)n * 64 + c] : 0.f;
    Wt[idx] = W_in[idx];
  }
  __syncthreads();

  float acc[4][4] = {};
  gemm64(Xt, 68, Wt, 64, acc, tn, tc);
#pragma unroll
  for (int i = 0; i < 4; ++i)
#pragma unroll
    for (int j = 0; j < 4; ++j) {
      float v = acc[i][j] + b_in[tc * 4 + j];
      Ht[(tn * 4 + i) * 68 + tc * 4 + j] = fmaxf(v, 0.f);
    }
  __syncthreads();

  // LayerNorm: 4 threads per node row
  {
    int nl = t >> 2, qq = t & 3;
    float s = 0.f, ss = 0.f;
#pragma unroll
    for (int c = qq * 16; c < qq * 16 + 16; ++c) {
      float v = Ht[nl * 68 + c];
      s += v; ss += v * v;
    }
    s += __shfl_xor(s, 1);  s += __shfl_xor(s, 2);
    ss += __shfl_xor(ss, 1); ss += __shfl_xor(ss, 2);
    float mu = s * (1.f / 64.f);
    float var = ss * (1.f / 64.f) - mu * mu;
    float rs = rsqrtf(var + 1e-5f);
#pragma unroll
    for (int c = qq * 16; c < qq * 16 + 16; ++c) {
      float v = (Ht[nl * 68 + c] - mu) * rs * ln_g[c] + ln_b[c];
      Ht[nl * 68 + c] = v;
    }
  }
  __syncthreads();

  const float* Ws[3] = {W_dst, W_src, W_lin};
  float* Og[3] = {qg, kg, vg};
#pragma unroll 1
  for (int m = 0; m < 3; ++m) {
#pragma unroll
    for (int r = 0; r < 16; ++r) {
      int idx = r * 256 + t;
      Wt[idx] = Ws[m][idx];
    }
    __syncthreads();
    float a2[4][4] = {};
    gemm64(Ht, 68, Wt, 64, a2, tn, tc);
#pragma unroll
    for (int i = 0; i < 4; ++i) {
      int n = n0 + tn * 4 + i;
      if (n < N)
        *(float4*)&Og[m][(size_t)n * 64 + tc * 4] =
            make_float4(a2[i][0], a2[i][1], a2[i][2], a2[i][3]);
    }
    __syncthreads();
  }
}

// ------------------------------ edge kernel --------------------------------

__global__ __launch_bounds__(256) void k_edge(
    const int* __restrict__ ssrc, const int* __restrict__ sdst,
    const float* __restrict__ pos, const float* __restrict__ qg,
    const float* __restrict__ kg, const float* __restrict__ vg,
    const float* __restrict__ pn_W1, const float* __restrict__ pn_b1,
    const float* __restrict__ pn_W2, const float* __restrict__ pn_b2,
    const float* __restrict__ an_W1, const float* __restrict__ an_b1,
    const float* __restrict__ an_W2, const float* __restrict__ an_b2,
    float* __restrict__ sg, float* __restrict__ accg, int E) {
  __shared__ __align__(16) float A[64 * 68];   // ai / a1 / ex
  __shared__ __align__(16) float D[64 * 68];   // delta, then payload
  __shared__ __align__(16) float Wt[64 * 64];
  __shared__ float PD[64 * 4];
  __shared__ int Ss[64], Sd[64];
  int t = threadIdx.x;
  int tn = t >> 4, tc = t & 15;
  long e0 = (long)blockIdx.x * 64;

  if (t < 64) {
    long e = e0 + t;
    int s_ = (e < E) ? ssrc[e] : 0;
    int d_ = (e < E) ? sdst[e] : 0;
    Ss[t] = s_; Sd[t] = d_;
    PD[t * 4 + 0] = pos[d_ * 3 + 0] - pos[s_ * 3 + 0];
    PD[t * 4 + 1] = pos[d_ * 3 + 1] - pos[s_ * 3 + 1];
    PD[t * 4 + 2] = pos[d_ * 3 + 2] - pos[s_ * 3 + 2];
  }
#pragma unroll
  for (int r = 0; r < 16; ++r) Wt[r * 256 + t] = pn_W2[r * 256 + t];
  __syncthreads();

  // layer1 of pos MLP (K=3): A = relu(pd @ pn_W1 + b1)
#pragma unroll
  for (int i = 0; i < 4; ++i) {
    int row = tn * 4 + i;
    float p0 = PD[row * 4 + 0], p1 = PD[row * 4 + 1], p2 = PD[row * 4 + 2];
#pragma unroll
    for (int j = 0; j < 4; ++j) {
      int c = tc * 4 + j;
      float v = fmaf(p0, pn_W1[c],
                fmaf(p1, pn_W1[64 + c],
                fmaf(p2, pn_W1[128 + c], pn_b1[c])));
      A[row * 68 + c] = fmaxf(v, 0.f);
    }
  }
  __syncthreads();

  // delta = relu(A @ pn_W2 + b2)  -> D
  {
    float acc[4][4] = {};
    gemm64(A, 68, Wt, 64, acc, tn, tc);
    __syncthreads();   // readers of A done before overwrite below
#pragma unroll
    for (int i = 0; i < 4; ++i)
#pragma unroll
      for (int j = 0; j < 4; ++j)
        D[(tn * 4 + i) * 68 + tc * 4 + j] =
            fmaxf(acc[i][j] + pn_b2[tc * 4 + j], 0.f);
  }
  __syncthreads();

  // A = q[dst]-k[src]+delta;  D (in place) = payload = v[src]+delta;  Wt = an_W1
#pragma unroll
  for (int r = 0; r < 16; ++r) {
    int idx = r * 256 + t;
    int el = idx >> 6, c = idx & 63;
    float dl = D[el * 68 + c];
    A[el * 68 + c] = qg[(size_t)Sd[el] * 64 + c] - kg[(size_t)Ss[el] * 64 + c] + dl;
    D[el * 68 + c] = vg[(size_t)Ss[el] * 64 + c] + dl;
    Wt[idx] = an_W1[idx];
  }
  __syncthreads();

  // a1 = relu(A @ an_W1 + an_b1) -> back into A;  Wt = an_W2
  {
    float acc[4][4] = {};
    gemm64(A, 68, Wt, 64, acc, tn, tc);
    __syncthreads();   // all reads of A / Wt complete
#pragma unroll
    for (int i = 0; i < 4; ++i)
#pragma unroll
      for (int j = 0; j < 4; ++j)
        A[(tn * 4 + i) * 68 + tc * 4 + j] =
            fmaxf(acc[i][j] + an_b1[tc * 4 + j], 0.f);
#pragma unroll
    for (int r = 0; r < 16; ++r) Wt[r * 256 + t] = an_W2[r * 256 + t];
  }
  __syncthreads();

  // alpha = relu(A @ an_W2 + an_b2); ex = exp(alpha) -> overwrite A
  {
    float acc[4][4] = {};
    gemm64(A, 68, Wt, 64, acc, tn, tc);
    __syncthreads();   // all gemm reads of A complete before overwrite
#pragma unroll
    for (int i = 0; i < 4; ++i) {
      int row = tn * 4 + i;
      long e = e0 + row;
#pragma unroll
      for (int j = 0; j < 4; ++j) {
        int c = tc * 4 + j;
        float al = fmaxf(acc[i][j] + an_b2[c], 0.f);
        A[row * 68 + c] = (e < E) ? __expf(al) : 0.f;   // invalid rows add 0
      }
    }
  }
  __syncthreads();

  // segmented per-dst reduction: 4 threads/channel, 16 sorted rows each.
  // One atomicAdd per (run, channel); runs split at chunk boundaries (safe).
  {
    int c = t & 63, q = t >> 6;
    int r0 = q * 16;
    int cur = Sd[r0];
    float ssum = 0.f, asum = 0.f;
#pragma unroll
    for (int r = r0; r < r0 + 16; ++r) {
      int d = Sd[r];
      if (d != cur) {
        if (ssum != 0.f) {
          atomicAdd(&sg[(size_t)cur * 64 + c], ssum);
          atomicAdd(&accg[(size_t)cur * 64 + c], asum);
        }
        cur = d; ssum = 0.f; asum = 0.f;
      }
      float ex = A[r * 68 + c];
      ssum += ex;
      asum = fmaf(ex, D[r * 68 + c], asum);
    }
    if (ssum != 0.f) {
      atomicAdd(&sg[(size_t)cur * 64 + c], ssum);
      atomicAdd(&accg[(size_t)cur * 64 + c], asum);
    }
  }
}

// ------------------------------ out kernel ---------------------------------

__global__ __launch_bounds__(256) void k_out(const float* __restrict__ accg,
                                             const float* __restrict__ sg,
                                             const float* __restrict__ W,
                                             const float* __restrict__ b,
                                             float* __restrict__ out, int N) {
  __shared__ __align__(16) float Xt[64 * 68];
  __shared__ __align__(16) float Wt[64 * 64];
  int t = threadIdx.x;
  int n0 = blockIdx.x * 64;
  int tn = t >> 4, tc = t & 15;
#pragma unroll
  for (int r = 0; r < 16; ++r) {
    int idx = r * 256 + t;
    int nl = idx >> 6, c = idx & 63;
    int n = n0 + nl;
    float v = 0.f;
    if (n < N) {
      size_t o = (size_t)n * 64 + c;
      v = accg[o] / (sg[o] + 1e-16f);
    }
    Xt[nl * 68 + c] = v;
    Wt[idx] = W[idx];
  }
  __syncthreads();
  float acc[4][4] = {};
  gemm64(Xt, 68, Wt, 64, acc, tn, tc);
#pragma unroll
  for (int i = 0; i < 4; ++i) {
    int n = n0 + tn * 4 + i;
    if (n < N) {
      float4 o;
      o.x = fmaxf(acc[i][0] + b[tc * 4 + 0], 0.f);
      o.y = fmaxf(acc[i][1] + b[tc * 4 + 1], 0.f);
      o.z = fmaxf(acc[i][2] + b[tc * 4 + 2], 0.f);
      o.w = fmaxf(acc[i][3] + b[tc * 4 + 3], 0.f);
      *(float4*)&out[(size_t)n * 64 + tc * 4] = o;
    }
  }
}

// ------------------------------- launcher ----------------------------------

extern "C" void kernel_launch(void* const* d_in, const int* in_sizes, int n_in,
                              void* d_out, int out_size, void* d_ws, size_t ws_size,
                              hipStream_t stream) {
  const float* x     = (const float*)d_in[0];
  const float* pos   = (const float*)d_in[1];
  const int*   eidx  = (const int*)d_in[2];
  const float* W_in  = (const float*)d_in[3];
  const float* b_in  = (const float*)d_in[4];
  const float* ln_g  = (const float*)d_in[5];
  const float* ln_b  = (const float*)d_in[6];
  const float* W_lin = (const float*)d_in[7];
  const float* W_src = (const float*)d_in[8];
  const float* W_dst = (const float*)d_in[9];
  const float* pn_W1 = (const float*)d_in[10];
  const float* pn_b1 = (const float*)d_in[11];
  const float* pn_W2 = (const float*)d_in[12];
  const float* pn_b2 = (const float*)d_in[13];
  const float* an_W1 = (const float*)d_in[14];
  const float* an_b1 = (const float*)d_in[15];
  const float* an_W2 = (const float*)d_in[16];
  const float* an_b2 = (const float*)d_in[17];
  const float* W_out = (const float*)d_in[18];
  const float* b_out = (const float*)d_in[19];
  float* out = (float*)d_out;

  int N = in_sizes[0] / 64;
  int E = in_sizes[2] / 2;
  const int* src = eidx;
  const int* dst = eidx + E;

  char* w = (char*)d_ws;
  auto alloc = [&](size_t bytes) -> void* {
    void* p = (void*)w;
    w += (bytes + 255) & ~(size_t)255;
    return p;
  };
  float* qg   = (float*)alloc((size_t)N * 64 * 4);
  float* kg   = (float*)alloc((size_t)N * 64 * 4);
  float* vg   = (float*)alloc((size_t)N * 64 * 4);
  float* sg   = (float*)alloc((size_t)N * 64 * 4);
  float* accg = (float*)alloc((size_t)N * 64 * 4);   // contiguous after sg
  int* ssrc   = (int*)alloc((size_t)E * 4);
  int* sdst   = (int*)alloc((size_t)E * 4);
  int* hist   = (int*)alloc((size_t)N * 4);
  int* cursor = (int*)alloc((size_t)N * 4);
  int* bsum   = (int*)alloc(1024 * 4);
  int* boff   = (int*)alloc(1024 * 4);
  int* incl   = (int*)accg;   // scan scratch aliased into accg (used first)

  int nb1 = (N + 1023) / 1024;

  // ---- sort edges by dst ----
  hipMemsetAsync(hist, 0, (size_t)N * 4, stream);
  k_hist<<<(E + 255) / 256, 256, 0, stream>>>(dst, hist, E);
  k_scan1<<<nb1, 256, 0, stream>>>(hist, incl, bsum, N);
  k_scan2<<<1, 128, 0, stream>>>(bsum, boff, nb1);
  k_scan3<<<nb1, 256, 0, stream>>>(incl, hist, boff, cursor, N);
  k_scatter<<<(E + 255) / 256, 256, 0, stream>>>(src, dst, cursor, ssrc, sdst, E);

  // ---- zero softmax accumulators (ws poisoned 0xAA each call) ----
  hipMemsetAsync(sg, 0, (size_t)N * 64 * 4 * 2, stream);

  k_node<<<(N + 63) / 64, 256, 0, stream>>>(x, W_in, b_in, ln_g, ln_b,
                                            W_dst, W_src, W_lin, qg, kg, vg, N);
  k_edge<<<(E + 63) / 64, 256, 0, stream>>>(ssrc, sdst, pos, qg, kg, vg,
                                            pn_W1, pn_b1, pn_W2, pn_b2,
                                            an_W1, an_b1, an_W2, an_b2,
                                            sg, accg, E);
  k_out<<<(N + 63) / 64, 256, 0, stream>>>(accg, sg, W_out, b_out, out, N);
}

// Round 4
// 796.464 us; speedup vs baseline: 3.6994x; 1.2750x over previous
//
#include <hip/hip_runtime.h>

// ---------------------------------------------------------------------------
// PointTransformerConv block, MI355X.  R4: k_edge GEMMs moved to bf16 MFMA
// (v_mfma_f32_16x16x32_bf16). Each wave owns 16 edges; weights staged once
// per block into LDS as bf16 [n][k] stride 72 (144B rows: 16B-aligned b128
// frag reads, 2-way banks = free). C->A layout transform via LDS bf16
// round-trip. Segmented per-dst-run reduction with one atomicAdd per run
// per channel (R3 scheme, unchanged).
//  MFMA layouts (HW-verified, guide §3): A[m=lane&15][k=quad*8+j],
//  B[k=quad*8+j][n=lane&15], C/D col=lane&15 row=quad*4+reg.
// ---------------------------------------------------------------------------

typedef __bf16 bf16x8 __attribute__((ext_vector_type(8)));
typedef float f32x4 __attribute__((ext_vector_type(4)));

__device__ inline unsigned short f2bf(float f) {
  unsigned int u = __float_as_uint(f);
  u += 0x7fffu + ((u >> 16) & 1u);   // round-to-nearest-even
  return (unsigned short)(u >> 16);
}
__device__ inline float bf2f(unsigned short s) {
  return __uint_as_float(((unsigned int)s) << 16);
}
__device__ inline bf16x8 ld_bf8(const unsigned short* p) {
  union { uint4 i; bf16x8 v; } u;
  u.i = *(const uint4*)p;
  return u.v;
}

// 64x64x64 fp32 GEMM from LDS tiles (k_node / k_out). tn=t/16, tc=t%16.
__device__ inline void gemm64(const float* A, int sa, const float* B, int sb,
                              float acc[4][4], int tn, int tc) {
#pragma unroll 2
  for (int k = 0; k < 64; k += 4) {
    float4 a[4], b[4];
#pragma unroll
    for (int i = 0; i < 4; ++i)
      a[i] = *(const float4*)(A + (tn * 4 + i) * sa + k);
#pragma unroll
    for (int kk = 0; kk < 4; ++kk)
      b[kk] = *(const float4*)(B + (k + kk) * sb + tc * 4);
#pragma unroll
    for (int i = 0; i < 4; ++i) {
      const float* av = (const float*)&a[i];
#pragma unroll
      for (int kk = 0; kk < 4; ++kk) {
        const float* bv = (const float*)&b[kk];
        acc[i][0] = fmaf(av[kk], bv[0], acc[i][0]);
        acc[i][1] = fmaf(av[kk], bv[1], acc[i][1]);
        acc[i][2] = fmaf(av[kk], bv[2], acc[i][2]);
        acc[i][3] = fmaf(av[kk], bv[3], acc[i][3]);
      }
    }
  }
}

// ------------------------------ sort kernels -------------------------------

__global__ void k_hist(const int* __restrict__ dst, int* __restrict__ hist, int E) {
  int e = blockIdx.x * 256 + threadIdx.x;
  if (e < E) atomicAdd(&hist[dst[e]], 1);
}

__global__ __launch_bounds__(256) void k_scan1(const int* __restrict__ hist,
                                               int* __restrict__ incl,
                                               int* __restrict__ bsum, int N) {
  __shared__ int sd[256];
  int t = threadIdx.x;
  int base = blockIdx.x * 1024 + t * 4;
  int v[4]; int ts = 0;
#pragma unroll
  for (int i = 0; i < 4; ++i) {
    int idx = base + i;
    v[i] = (idx < N) ? hist[idx] : 0;
    ts += v[i];
  }
  sd[t] = ts;
  __syncthreads();
  for (int off = 1; off < 256; off <<= 1) {
    int xv = (t >= off) ? sd[t - off] : 0;
    __syncthreads();
    sd[t] += xv;
    __syncthreads();
  }
  int run = sd[t] - ts;
#pragma unroll
  for (int i = 0; i < 4; ++i) {
    run += v[i];
    int idx = base + i;
    if (idx < N) incl[idx] = run;
  }
  if (t == 255) bsum[blockIdx.x] = sd[255];
}

__global__ void k_scan2(const int* __restrict__ bsum, int* __restrict__ boff, int nb) {
  __shared__ int sd[128];
  int t = threadIdx.x;
  int v = (t < nb) ? bsum[t] : 0;
  sd[t] = v;
  __syncthreads();
  for (int off = 1; off < 128; off <<= 1) {
    int xv = (t >= off) ? sd[t - off] : 0;
    __syncthreads();
    sd[t] += xv;
    __syncthreads();
  }
  if (t < nb) boff[t] = sd[t] - v;
}

__global__ void k_scan3(const int* __restrict__ incl, const int* __restrict__ hist,
                        const int* __restrict__ boff, int* __restrict__ cursor,
                        int N) {
  int base = blockIdx.x * 1024 + threadIdx.x * 4;
  int bo = boff[blockIdx.x];
#pragma unroll
  for (int i = 0; i < 4; ++i) {
    int id = base + i;
    if (id < N) cursor[id] = bo + incl[id] - hist[id];
  }
}

__global__ void k_scatter(const int* __restrict__ src, const int* __restrict__ dst,
                          int* __restrict__ cursor, int* __restrict__ ssrc,
                          int* __restrict__ sdst, int E) {
  int e = blockIdx.x * 256 + threadIdx.x;
  if (e < E) {
    int d = dst[e];
    int p = atomicAdd(&cursor[d], 1);
    ssrc[p] = src[e];
    sdst[p] = d;
  }
}

// ------------------------------ node kernel --------------------------------

__global__ __launch_bounds__(256) void k_node(
    const float* __restrict__ x, const float* __restrict__ W_in,
    const float* __restrict__ b_in, const float* __restrict__ ln_g,
    const float* __restrict__ ln_b, const float* __restrict__ W_dst,
    const float* __restrict__ W_src, const float* __restrict__ W_lin,
    float* __restrict__ qg, float* __restrict__ kg, float* __restrict__ vg, int N) {
  __shared__ __align__(16) float Xt[64 * 68];
  __shared__ __align__(16) float Ht[64 * 68];
  __shared__ __align__(16) float Wt[64 * 64];
  int t = threadIdx.x;
  int n0 = blockIdx.x * 64;
  int tn = t >> 4, tc = t & 15;

#pragma unroll
  for (int r = 0; r < 16; ++r) {
    int idx = r * 256 + t;
    int nl = idx >> 6, c = idx & 63;
    int n = n0 + nl;
    Xt[nl * 68 + c] = (n < N) ? x[(size_t)n * 64 + c] : 0.f;
    Wt[idx] = W_in[idx];
  }
  __syncthreads();

  float acc[4][4] = {};
  gemm64(Xt, 68, Wt, 64, acc, tn, tc);
#pragma unroll
  for (int i = 0; i < 4; ++i)
#pragma unroll
    for (int j = 0; j < 4; ++j) {
      float v = acc[i][j] + b_in[tc * 4 + j];
      Ht[(tn * 4 + i) * 68 + tc * 4 + j] = fmaxf(v, 0.f);
    }
  __syncthreads();

  {
    int nl = t >> 2, qq = t & 3;
    float s = 0.f, ss = 0.f;
#pragma unroll
    for (int c = qq * 16; c < qq * 16 + 16; ++c) {
      float v = Ht[nl * 68 + c];
      s += v; ss += v * v;
    }
    s += __shfl_xor(s, 1);  s += __shfl_xor(s, 2);
    ss += __shfl_xor(ss, 1); ss += __shfl_xor(ss, 2);
    float mu = s * (1.f / 64.f);
    float var = ss * (1.f / 64.f) - mu * mu;
    float rs = rsqrtf(var + 1e-5f);
#pragma unroll
    for (int c = qq * 16; c < qq * 16 + 16; ++c) {
      float v = (Ht[nl * 68 + c] - mu) * rs * ln_g[c] + ln_b[c];
      Ht[nl * 68 + c] = v;
    }
  }
  __syncthreads();

  const float* Ws[3] = {W_dst, W_src, W_lin};
  float* Og[3] = {qg, kg, vg};
#pragma unroll 1
  for (int m = 0; m < 3; ++m) {
#pragma unroll
    for (int r = 0; r < 16; ++r) {
      int idx = r * 256 + t;
      Wt[idx] = Ws[m][idx];
    }
    __syncthreads();
    float a2[4][4] = {};
    gemm64(Ht, 68, Wt, 64, a2, tn, tc);
#pragma unroll
    for (int i = 0; i < 4; ++i) {
      int n = n0 + tn * 4 + i;
      if (n < N)
        *(float4*)&Og[m][(size_t)n * 64 + tc * 4] =
            make_float4(a2[i][0], a2[i][1], a2[i][2], a2[i][3]);
    }
    __syncthreads();
  }
}

// ------------------------- edge kernel (MFMA) ------------------------------

__global__ __launch_bounds__(256) void k_edge(
    const int* __restrict__ ssrc, const int* __restrict__ sdst,
    const float* __restrict__ pos, const float* __restrict__ qg,
    const float* __restrict__ kg, const float* __restrict__ vg,
    const float* __restrict__ pn_W1, const float* __restrict__ pn_b1,
    const float* __restrict__ pn_W2, const float* __restrict__ pn_b2,
    const float* __restrict__ an_W1, const float* __restrict__ an_b1,
    const float* __restrict__ an_W2, const float* __restrict__ an_b2,
    float* __restrict__ sg, float* __restrict__ accg, int E) {
  // bf16 weights transposed to [n][k], stride 72 (144B rows: 16B-aligned b128)
  __shared__ __align__(16) unsigned short WPN2[64 * 72];
  __shared__ __align__(16) unsigned short WAN1[64 * 72];
  __shared__ __align__(16) unsigned short WAN2[64 * 72];
  __shared__ __align__(16) unsigned short SD[64 * 72];   // delta (bf16)
  __shared__ __align__(16) unsigned short SB[64 * 72];   // a1, then ex (bf16)
  __shared__ float PD[64 * 4];
  __shared__ float W1[3 * 64];   // pn_W1
  __shared__ float B1[64], B2[64], AB1[64], AB2[64];
  __shared__ int Ss[64], Sd[64];

  int t = threadIdx.x;
  int lane = t & 63, wv = t >> 6;
  int nl = lane & 15, q = lane >> 4;
  int w16 = wv * 16;
  long e0 = (long)blockIdx.x * 64;

  // ---- stage weights (coalesced global reads; LDS writes cold-path) ----
  {
    int n = t & 63, k0 = (t >> 6) * 16;
#pragma unroll
    for (int i = 0; i < 16; ++i) {
      int k = k0 + i;
      WPN2[n * 72 + k] = f2bf(pn_W2[k * 64 + n]);
      WAN1[n * 72 + k] = f2bf(an_W1[k * 64 + n]);
      WAN2[n * 72 + k] = f2bf(an_W2[k * 64 + n]);
    }
  }
  if (t < 192) W1[t] = pn_W1[t];
  if (t < 64) {
    B1[t] = pn_b1[t];  B2[t] = pn_b2[t];
    AB1[t] = an_b1[t]; AB2[t] = an_b2[t];
    long e = e0 + t;
    int s_ = (e < E) ? ssrc[e] : 0;
    int d_ = (e < E) ? sdst[e] : 0;
    Ss[t] = s_; Sd[t] = d_;
    PD[t * 4 + 0] = pos[d_ * 3 + 0] - pos[s_ * 3 + 0];
    PD[t * 4 + 1] = pos[d_ * 3 + 1] - pos[s_ * 3 + 1];
    PD[t * 4 + 2] = pos[d_ * 3 + 2] - pos[s_ * 3 + 2];
  }
  __syncthreads();

  bf16x8 a[2];

  // ---- pos-MLP layer1 (K=3) straight into A-frag registers ----
  {
    int row = w16 + nl;
    float p0 = PD[row * 4 + 0], p1 = PD[row * 4 + 1], p2 = PD[row * 4 + 2];
#pragma unroll
    for (int s = 0; s < 2; ++s) {
      union { unsigned short u[8]; bf16x8 v; } fa;
      int kb = s * 32 + q * 8;
#pragma unroll
      for (int j = 0; j < 8; ++j) {
        int c = kb + j;
        float val = fmaf(p0, W1[c],
                    fmaf(p1, W1[64 + c],
                    fmaf(p2, W1[128 + c], B1[c])));
        fa.u[j] = f2bf(fmaxf(val, 0.f));
      }
      a[s] = fa.v;
    }
  }

  // ---- GEMM1: delta = relu(A1 @ pn_W2 + b2) -> SD (bf16) ----
#pragma unroll
  for (int n0 = 0; n0 < 4; ++n0) {
    f32x4 acc = {0.f, 0.f, 0.f, 0.f};
    acc = __builtin_amdgcn_mfma_f32_16x16x32_bf16(
        a[0], ld_bf8(&WPN2[(n0 * 16 + nl) * 72 + q * 8]), acc, 0, 0, 0);
    acc = __builtin_amdgcn_mfma_f32_16x16x32_bf16(
        a[1], ld_bf8(&WPN2[(n0 * 16 + nl) * 72 + 32 + q * 8]), acc, 0, 0, 0);
    int col = n0 * 16 + nl;
    float bias = B2[col];
#pragma unroll
    for (int r = 0; r < 4; ++r) {
      int row = w16 + q * 4 + r;
      SD[row * 72 + col] = f2bf(fmaxf(acc[r] + bias, 0.f));
    }
  }

  // ---- build ai = q[dst]-k[src]+delta in A-frag layout ----
  {
    int row = w16 + nl;
    const float* qr = qg + (size_t)Sd[row] * 64;
    const float* kr = kg + (size_t)Ss[row] * 64;
#pragma unroll
    for (int s = 0; s < 2; ++s) {
      int kb = s * 32 + q * 8;
      float4 qa = *(const float4*)(qr + kb);
      float4 qb = *(const float4*)(qr + kb + 4);
      float4 ka = *(const float4*)(kr + kb);
      float4 kb4 = *(const float4*)(kr + kb + 4);
      bf16x8 d8 = ld_bf8(&SD[row * 72 + kb]);
      union { unsigned short u[8]; bf16x8 v; } fa;
      fa.u[0] = f2bf(qa.x - ka.x + (float)d8[0]);
      fa.u[1] = f2bf(qa.y - ka.y + (float)d8[1]);
      fa.u[2] = f2bf(qa.z - ka.z + (float)d8[2]);
      fa.u[3] = f2bf(qa.w - ka.w + (float)d8[3]);
      fa.u[4] = f2bf(qb.x - kb4.x + (float)d8[4]);
      fa.u[5] = f2bf(qb.y - kb4.y + (float)d8[5]);
      fa.u[6] = f2bf(qb.z - kb4.z + (float)d8[6]);
      fa.u[7] = f2bf(qb.w - kb4.w + (float)d8[7]);
      a[s] = fa.v;
    }
  }

  // ---- GEMM2: a1 = relu(ai @ an_W1 + an_b1) -> SB (bf16) ----
#pragma unroll
  for (int n0 = 0; n0 < 4; ++n0) {
    f32x4 acc = {0.f, 0.f, 0.f, 0.f};
    acc = __builtin_amdgcn_mfma_f32_16x16x32_bf16(
        a[0], ld_bf8(&WAN1[(n0 * 16 + nl) * 72 + q * 8]), acc, 0, 0, 0);
    acc = __builtin_amdgcn_mfma_f32_16x16x32_bf16(
        a[1], ld_bf8(&WAN1[(n0 * 16 + nl) * 72 + 32 + q * 8]), acc, 0, 0, 0);
    int col = n0 * 16 + nl;
    float bias = AB1[col];
#pragma unroll
    for (int r = 0; r < 4; ++r) {
      int row = w16 + q * 4 + r;
      SB[row * 72 + col] = f2bf(fmaxf(acc[r] + bias, 0.f));
    }
  }

  // ---- GEMM3: alpha = relu(a1 @ an_W2 + an_b2); ex = exp(alpha) -> SB ----
  // (a-frag reads precede the ex overwrite; DS pipe is in-order per wave,
  //  and regions are wave-private, so no barrier needed.)
  a[0] = ld_bf8(&SB[(w16 + nl) * 72 + q * 8]);
  a[1] = ld_bf8(&SB[(w16 + nl) * 72 + 32 + q * 8]);
#pragma unroll
  for (int n0 = 0; n0 < 4; ++n0) {
    f32x4 acc = {0.f, 0.f, 0.f, 0.f};
    acc = __builtin_amdgcn_mfma_f32_16x16x32_bf16(
        a[0], ld_bf8(&WAN2[(n0 * 16 + nl) * 72 + q * 8]), acc, 0, 0, 0);
    acc = __builtin_amdgcn_mfma_f32_16x16x32_bf16(
        a[1], ld_bf8(&WAN2[(n0 * 16 + nl) * 72 + 32 + q * 8]), acc, 0, 0, 0);
    int col = n0 * 16 + nl;
    float bias = AB2[col];
#pragma unroll
    for (int r = 0; r < 4; ++r) {
      int row = w16 + q * 4 + r;
      long e = e0 + row;
      float al = fmaxf(acc[r] + bias, 0.f);
      float ex = (e < E) ? __expf(al) : 0.f;
      SB[row * 72 + col] = f2bf(ex);
    }
  }
  __syncthreads();

  // ---- segmented per-dst-run reduction; one atomicAdd per run/channel ----
  {
    int c = t & 63, qq = t >> 6;
    int r0 = qq * 16;
    int cur = Sd[r0];
    float ssum = 0.f, asum = 0.f;
#pragma unroll
    for (int r = r0; r < r0 + 16; ++r) {
      int d = Sd[r];
      if (d != cur) {
        if (ssum != 0.f) {
          atomicAdd(&sg[(size_t)cur * 64 + c], ssum);
          atomicAdd(&accg[(size_t)cur * 64 + c], asum);
        }
        cur = d; ssum = 0.f; asum = 0.f;
      }
      float ex = bf2f(SB[r * 72 + c]);
      float pay = vg[(size_t)Ss[r] * 64 + c] + bf2f(SD[r * 72 + c]);
      ssum += ex;
      asum = fmaf(ex, pay, asum);
    }
    if (ssum != 0.f) {
      atomicAdd(&sg[(size_t)cur * 64 + c], ssum);
      atomicAdd(&accg[(size_t)cur * 64 + c], asum);
    }
  }
}

// ------------------------------ out kernel ---------------------------------

__global__ __launch_bounds__(256) void k_out(const float* __restrict__ accg,
                                             const float* __restrict__ sg,
                                             const float* __restrict__ W,
                                             const float* __restrict__ b,
                                             float* __restrict__ out, int N) {
  __shared__ __align__(16) float Xt[64 * 68];
  __shared__ __align__(16) float Wt[64 * 64];
  int t = threadIdx.x;
  int n0 = blockIdx.x * 64;
  int tn = t >> 4, tc = t & 15;
#pragma unroll
  for (int r = 0; r < 16; ++r) {
    int idx = r * 256 + t;
    int nl = idx >> 6, c = idx & 63;
    int n = n0 + nl;
    float v = 0.f;
    if (n < N) {
      size_t o = (size_t)n * 64 + c;
      v = accg[o] / (sg[o] + 1e-16f);
    }
    Xt[nl * 68 + c] = v;
    Wt[idx] = W[idx];
  }
  __syncthreads();
  float acc[4][4] = {};
  gemm64(Xt, 68, Wt, 64, acc, tn, tc);
#pragma unroll
  for (int i = 0; i < 4; ++i) {
    int n = n0 + tn * 4 + i;
    if (n < N) {
      float4 o;
      o.x = fmaxf(acc[i][0] + b[tc * 4 + 0], 0.f);
      o.y = fmaxf(acc[i][1] + b[tc * 4 + 1], 0.f);
      o.z = fmaxf(acc[i][2] + b[tc * 4 + 2], 0.f);
      o.w = fmaxf(acc[i][3] + b[tc * 4 + 3], 0.f);
      *(float4*)&out[(size_t)n * 64 + tc * 4] = o;
    }
  }
}

// ------------------------------- launcher ----------------------------------

extern "C" void kernel_launch(void* const* d_in, const int* in_sizes, int n_in,
                              void* d_out, int out_size, void* d_ws, size_t ws_size,
                              hipStream_t stream) {
  const float* x     = (const float*)d_in[0];
  const float* pos   = (const float*)d_in[1];
  const int*   eidx  = (const int*)d_in[2];
  const float* W_in  = (const float*)d_in[3];
  const float* b_in  = (const float*)d_in[4];
  const float* ln_g  = (const float*)d_in[5];
  const float* ln_b  = (const float*)d_in[6];
  const float* W_lin = (const float*)d_in[7];
  const float* W_src = (const float*)d_in[8];
  const float* W_dst = (const float*)d_in[9];
  const float* pn_W1 = (const float*)d_in[10];
  const float* pn_b1 = (const float*)d_in[11];
  const float* pn_W2 = (const float*)d_in[12];
  const float* pn_b2 = (const float*)d_in[13];
  const float* an_W1 = (const float*)d_in[14];
  const float* an_b1 = (const float*)d_in[15];
  const float* an_W2 = (const float*)d_in[16];
  const float* an_b2 = (const float*)d_in[17];
  const float* W_out = (const float*)d_in[18];
  const float* b_out = (const float*)d_in[19];
  float* out = (float*)d_out;

  int N = in_sizes[0] / 64;
  int E = in_sizes[2] / 2;
  const int* src = eidx;
  const int* dst = eidx + E;

  char* w = (char*)d_ws;
  auto alloc = [&](size_t bytes) -> void* {
    void* p = (void*)w;
    w += (bytes + 255) & ~(size_t)255;
    return p;
  };
  float* qg   = (float*)alloc((size_t)N * 64 * 4);
  float* kg   = (float*)alloc((size_t)N * 64 * 4);
  float* vg   = (float*)alloc((size_t)N * 64 * 4);
  float* sg   = (float*)alloc((size_t)N * 64 * 4);
  float* accg = (float*)alloc((size_t)N * 64 * 4);   // contiguous after sg
  int* ssrc   = (int*)alloc((size_t)E * 4);
  int* sdst   = (int*)alloc((size_t)E * 4);
  int* hist   = (int*)alloc((size_t)N * 4);
  int* cursor = (int*)alloc((size_t)N * 4);
  int* bsum   = (int*)alloc(1024 * 4);
  int* boff   = (int*)alloc(1024 * 4);
  int* incl   = (int*)accg;   // scan scratch aliased into accg (used first)

  int nb1 = (N + 1023) / 1024;

  // ---- sort edges by dst ----
  hipMemsetAsync(hist, 0, (size_t)N * 4, stream);
  k_hist<<<(E + 255) / 256, 256, 0, stream>>>(dst, hist, E);
  k_scan1<<<nb1, 256, 0, stream>>>(hist, incl, bsum, N);
  k_scan2<<<1, 128, 0, stream>>>(bsum, boff, nb1);
  k_scan3<<<nb1, 256, 0, stream>>>(incl, hist, boff, cursor, N);
  k_scatter<<<(E + 255) / 256, 256, 0, stream>>>(src, dst, cursor, ssrc, sdst, E);

  // ---- zero softmax accumulators (ws poisoned 0xAA each call) ----
  hipMemsetAsync(sg, 0, (size_t)N * 64 * 4 * 2, stream);

  k_node<<<(N + 63) / 64, 256, 0, stream>>>(x, W_in, b_in, ln_g, ln_b,
                                            W_dst, W_src, W_lin, qg, kg, vg, N);
  k_edge<<<(E + 63) / 64, 256, 0, stream>>>(ssrc, sdst, pos, qg, kg, vg,
                                            pn_W1, pn_b1, pn_W2, pn_b2,
                                            an_W1, an_b1, an_W2, an_b2,
                                            sg, accg, E);
  k_out<<<(N + 63) / 64, 256, 0, stream>>>(accg, sg, W_out, b_out, out, N);
}